// Round 1
// baseline (615.234 us; speedup 1.0000x reference)
//
#include <hip/hip_runtime.h>
#include <hip/hip_bf16.h>
#include <stdint.h>

typedef __bf16 bf16;
typedef bf16 bf16x8 __attribute__((ext_vector_type(8)));
typedef bf16 bf16x4 __attribute__((ext_vector_type(4)));
typedef float f32x4 __attribute__((ext_vector_type(4)));

#define DEV static __device__ __forceinline__

constexpr int Bc = 16, Tc = 1029, Cc = 1024, Hc = 16, Dc = 64;
constexpr int TPAD = 1056;     // 33 * 32
constexpr int MPAD = 16512;    // 129 * 128
constexpr int NQT  = TPAD / 32;  // 33

DEV void gload16(void* lds_dst, const void* gsrc) {
  __builtin_amdgcn_global_load_lds(
      (const __attribute__((address_space(1))) void*)gsrc,
      (__attribute__((address_space(3))) void*)lds_dst, 16, 0, 0);
}

// ---------------- cast x (f32 -> bf16), zero pad rows ----------------
__global__ __launch_bounds__(256) void cast_x(const float* __restrict__ x,
                                              bf16* __restrict__ xb) {
  const size_t i = ((size_t)blockIdx.x * 256 + threadIdx.x) * 8;
  const int row = (int)(i >> 10);
  bf16x8 o = {};
  if (row < Bc * Tc) {
    const float4* p = (const float4*)(x + i);
    float4 a = p[0], b = p[1];
    o[0] = (bf16)a.x; o[1] = (bf16)a.y; o[2] = (bf16)a.z; o[3] = (bf16)a.w;
    o[4] = (bf16)b.x; o[5] = (bf16)b.y; o[6] = (bf16)b.z; o[7] = (bf16)b.w;
  }
  *(bf16x8*)(xb + i) = o;
}

// ---------------- transpose + cast: W[rows][cols] f32 -> Wt[cols][rows] bf16
__global__ __launch_bounds__(256) void transpose_cast(const float* __restrict__ W,
                                                      bf16* __restrict__ Wt,
                                                      int rows, int cols) {
  __shared__ float tile[32][33];
  const int c0 = blockIdx.x * 32;
  const int r0 = blockIdx.y * 32;
  const int tr = threadIdx.x >> 5;   // 0..7
  const int tc = threadIdx.x & 31;   // 0..31
#pragma unroll
  for (int j = 0; j < 4; ++j)
    tile[tr + j * 8][tc] = W[(size_t)(r0 + tr + j * 8) * cols + c0 + tc];
  __syncthreads();
#pragma unroll
  for (int j = 0; j < 4; ++j)
    Wt[(size_t)(c0 + tr + j * 8) * rows + r0 + tc] = (bf16)tile[tc][tr + j * 8];
}

// ---------------- GEMM: C = A @ Bt^T + bias ----------------
// A [Mt][K] bf16 row-major (Mt mult of 128), Bt [N][K] bf16 row-major.
template <bool OUT_BF16>
__global__ __launch_bounds__(256) void gemm_bt(const bf16* __restrict__ A,
                                               const bf16* __restrict__ Bt,
                                               const float* __restrict__ bias,
                                               void* __restrict__ Cout,
                                               int N, int K, int Mlim) {
  constexpr int BM = 128, BN = 128, BK = 32;
  __shared__ bf16 As[2][BM * BK];
  __shared__ bf16 Bs[2][BN * BK];
  const int tid  = threadIdx.x;
  const int lane = tid & 63;
  const int wave = tid >> 6;
  const int g = lane >> 4;
  const int c = lane & 15;
  const int m0 = blockIdx.y * BM;
  const int n0 = blockIdx.x * BN;
  const int wm = (wave >> 1) * 64;
  const int wn = (wave & 1) * 64;

  auto stage = [&](int buf, int k0) {
#pragma unroll
    for (int j = 0; j < 2; ++j) {
      int idx = j * 256 + tid;
      int row = idx >> 2, ch = idx & 3;
      gload16(&As[buf][idx * 8], A + (size_t)(m0 + row) * K + k0 + ch * 8);
    }
#pragma unroll
    for (int j = 0; j < 2; ++j) {
      int idx = j * 256 + tid;
      int row = idx >> 2, ch = idx & 3;
      gload16(&Bs[buf][idx * 8], Bt + (size_t)(n0 + row) * K + k0 + ch * 8);
    }
  };

  f32x4 acc[4][4] = {};
  stage(0, 0);
  __syncthreads();
  const int nk = K / BK;
  for (int kt = 0; kt < nk; ++kt) {
    const int buf = kt & 1;
    if (kt + 1 < nk) stage(buf ^ 1, (kt + 1) * BK);
    bf16x8 af[4], bfr[4];
#pragma unroll
    for (int i = 0; i < 4; ++i) {
      af[i]  = *(const bf16x8*)&As[buf][(wm + i * 16 + c) * BK + g * 8];
      bfr[i] = *(const bf16x8*)&Bs[buf][(wn + i * 16 + c) * BK + g * 8];
    }
#pragma unroll
    for (int i = 0; i < 4; ++i)
#pragma unroll
      for (int j = 0; j < 4; ++j)
        acc[i][j] = __builtin_amdgcn_mfma_f32_16x16x32_bf16(af[i], bfr[j], acc[i][j], 0, 0, 0);
    __syncthreads();
  }

#pragma unroll
  for (int i = 0; i < 4; ++i) {
    const int mb = m0 + wm + i * 16 + g * 4;
#pragma unroll
    for (int j = 0; j < 4; ++j) {
      const int n = n0 + wn + j * 16 + c;
      const float bv = bias[n];
#pragma unroll
      for (int r = 0; r < 4; ++r) {
        const int m = mb + r;
        if (m < Mlim) {
          float v = acc[i][j][r] + bv;
          if constexpr (OUT_BF16)
            ((bf16*)Cout)[(size_t)m * N + n] = (bf16)v;
          else
            ((float*)Cout)[(size_t)m * N + n] = v;
        }
      }
    }
  }
}

// ---------------- RoPE + reshape Q,K -> [bh][TPAD][64] ----------------
__global__ __launch_bounds__(256) void rope_qk(const bf16* __restrict__ qkv,
                                               const float* __restrict__ cosT,
                                               const float* __restrict__ sinT,
                                               const int* __restrict__ npfx_p,
                                               bf16* __restrict__ Qh,
                                               bf16* __restrict__ Kh) {
  const int bt = blockIdx.x;
  const int b = bt / TPAD, t = bt % TPAD;
  const int h  = threadIdx.x >> 4;
  const int d0 = (threadIdx.x & 15) * 4;
  const size_t outoff = (((size_t)(b * Hc + h)) * TPAD + t) * Dc + d0;
  if (t >= Tc) {
    bf16x4 z = {};
    *(bf16x4*)(Qh + outoff) = z;
    *(bf16x4*)(Kh + outoff) = z;
    return;
  }
  const int npfx = *npfx_p;
  const size_t inb = ((size_t)b * Tc + t) * 3072 + h * Dc;
  bf16x4 qv = *(const bf16x4*)(qkv + inb + d0);
  bf16x4 kv = *(const bf16x4*)(qkv + inb + 1024 + d0);
  float q[4], k[4];
#pragma unroll
  for (int u = 0; u < 4; ++u) { q[u] = (float)qv[u]; k[u] = (float)kv[u]; }
  if (t >= npfx) {
    const int p  = t - npfx;
    const int dp = (d0 < 32) ? d0 + 32 : d0 - 32;
    const float sgn = (d0 < 32) ? -1.f : 1.f;
    bf16x4 qp = *(const bf16x4*)(qkv + inb + dp);
    bf16x4 kp = *(const bf16x4*)(qkv + inb + 1024 + dp);
    float4 csv = *(const float4*)(cosT + (size_t)p * Dc + d0);
    float4 snv = *(const float4*)(sinT + (size_t)p * Dc + d0);
    float cs[4] = {csv.x, csv.y, csv.z, csv.w};
    float sn[4] = {snv.x, snv.y, snv.z, snv.w};
#pragma unroll
    for (int u = 0; u < 4; ++u) {
      q[u] = q[u] * cs[u] + sgn * (float)qp[u] * sn[u];
      k[u] = k[u] * cs[u] + sgn * (float)kp[u] * sn[u];
    }
  }
  bf16x4 qo, ko;
#pragma unroll
  for (int u = 0; u < 4; ++u) {
    qo[u] = (bf16)(q[u] * 0.125f);  // fold 1/sqrt(D)
    ko[u] = (bf16)k[u];
  }
  *(bf16x4*)(Qh + outoff) = qo;
  *(bf16x4*)(Kh + outoff) = ko;
}

// ---------------- V transpose -> Vt [bh][64][TPAD] ----------------
__global__ __launch_bounds__(256) void vtrans(const bf16* __restrict__ qkv,
                                              bf16* __restrict__ Vt) {
  __shared__ bf16 lds[64][40];
  const int blk = blockIdx.x;
  const int tt = blk % NQT;
  const int bh = blk / NQT;
  const int b = bh >> 4, h = bh & 15;
  const int t0 = tt * 32;
  const int tl = threadIdx.x >> 3;  // 0..31
  const int ch = threadIdx.x & 7;   // 0..7
  bf16x8 v = {};
  const int t = t0 + tl;
  if (t < Tc)
    v = *(const bf16x8*)(qkv + ((size_t)b * Tc + t) * 3072 + 2048 + h * Dc + ch * 8);
#pragma unroll
  for (int u = 0; u < 8; ++u) lds[ch * 8 + u][tl] = v[u];
  __syncthreads();
  const int d  = threadIdx.x >> 2;  // 0..63
  const int tc = threadIdx.x & 3;   // 0..3
  bf16x8 o = *(const bf16x8*)&lds[d][tc * 8];
  *(bf16x8*)(Vt + ((size_t)bh * Dc + d) * TPAD + t0 + tc * 8) = o;
}

// ---------------- flash attention, 1 wave per 32-query tile ----------------
__global__ __launch_bounds__(64) void attn(const bf16* __restrict__ Qh,
                                           const bf16* __restrict__ Kh,
                                           const bf16* __restrict__ Vt,
                                           bf16* __restrict__ y2d) {
  __shared__ bf16 Pl[32][32];
  const int bid = blockIdx.x;
  const int qt = bid % NQT;
  const int bh = bid / NQT;
  const int b = bh >> 4, h = bh & 15;
  const int lane = threadIdx.x;
  const int g = lane >> 4, c = lane & 15;
  const int q0 = qt * 32;
  const bf16* Qb = Qh + ((size_t)bh * TPAD) * Dc;
  const bf16* Kb = Kh + ((size_t)bh * TPAD) * Dc;
  const bf16* Vb = Vt + ((size_t)bh * Dc) * TPAD;

  bf16x8 qf[2][2];
#pragma unroll
  for (int fm = 0; fm < 2; ++fm)
#pragma unroll
    for (int kc = 0; kc < 2; ++kc)
      qf[fm][kc] = *(const bf16x8*)(Qb + (size_t)(q0 + fm * 16 + c) * Dc + kc * 32 + g * 8);

  float mrun[2][4], lrun[2][4];
  f32x4 oacc[2][4] = {};
#pragma unroll
  for (int fm = 0; fm < 2; ++fm)
#pragma unroll
    for (int r = 0; r < 4; ++r) { mrun[fm][r] = -1e30f; lrun[fm][r] = 0.f; }

  for (int kt = 0; kt < NQT; ++kt) {
    const int k0 = kt * 32;
    f32x4 s[2][2] = {};
#pragma unroll
    for (int fn = 0; fn < 2; ++fn) {
#pragma unroll
      for (int kc = 0; kc < 2; ++kc) {
        bf16x8 kf = *(const bf16x8*)(Kb + (size_t)(k0 + fn * 16 + c) * Dc + kc * 32 + g * 8);
#pragma unroll
        for (int fm = 0; fm < 2; ++fm)
          s[fm][fn] = __builtin_amdgcn_mfma_f32_16x16x32_bf16(qf[fm][kc], kf, s[fm][fn], 0, 0, 0);
      }
      if (k0 + fn * 16 + c >= Tc) {
#pragma unroll
        for (int fm = 0; fm < 2; ++fm)
#pragma unroll
          for (int r = 0; r < 4; ++r) s[fm][fn][r] = -1e30f;
      }
    }
#pragma unroll
    for (int fm = 0; fm < 2; ++fm) {
      f32x4 mx;
#pragma unroll
      for (int r = 0; r < 4; ++r) mx[r] = fmaxf(s[fm][0][r], s[fm][1][r]);
#pragma unroll
      for (int msk = 1; msk < 16; msk <<= 1)
#pragma unroll
        for (int r = 0; r < 4; ++r) mx[r] = fmaxf(mx[r], __shfl_xor(mx[r], msk));
      float alpha[4];
#pragma unroll
      for (int r = 0; r < 4; ++r) {
        float mnew = fmaxf(mrun[fm][r], mx[r]);
        alpha[r] = __expf(mrun[fm][r] - mnew);
        mrun[fm][r] = mnew;
      }
      f32x4 psum = {};
#pragma unroll
      for (int fn = 0; fn < 2; ++fn) {
#pragma unroll
        for (int r = 0; r < 4; ++r) {
          float p = __expf(s[fm][fn][r] - mrun[fm][r]);
          psum[r] += p;
          Pl[fm * 16 + g * 4 + r][fn * 16 + c] = (bf16)p;
        }
      }
#pragma unroll
      for (int msk = 1; msk < 16; msk <<= 1)
#pragma unroll
        for (int r = 0; r < 4; ++r) psum[r] += __shfl_xor(psum[r], msk);
#pragma unroll
      for (int r = 0; r < 4; ++r) lrun[fm][r] = lrun[fm][r] * alpha[r] + psum[r];
#pragma unroll
      for (int fd = 0; fd < 4; ++fd)
#pragma unroll
        for (int r = 0; r < 4; ++r) oacc[fm][fd][r] *= alpha[r];
    }
    __syncthreads();
    bf16x8 pf[2];
#pragma unroll
    for (int fm = 0; fm < 2; ++fm) pf[fm] = *(const bf16x8*)&Pl[fm * 16 + c][g * 8];
#pragma unroll
    for (int fd = 0; fd < 4; ++fd) {
      bf16x8 vf = *(const bf16x8*)(Vb + (size_t)(fd * 16 + c) * TPAD + k0 + g * 8);
#pragma unroll
      for (int fm = 0; fm < 2; ++fm)
        oacc[fm][fd] = __builtin_amdgcn_mfma_f32_16x16x32_bf16(pf[fm], vf, oacc[fm][fd], 0, 0, 0);
    }
    __syncthreads();
  }

#pragma unroll
  for (int fm = 0; fm < 2; ++fm)
#pragma unroll
    for (int r = 0; r < 4; ++r) {
      const int trow = q0 + fm * 16 + g * 4 + r;
      if (trow < Tc) {
        const float inv = 1.f / lrun[fm][r];
#pragma unroll
        for (int fd = 0; fd < 4; ++fd)
          y2d[((size_t)b * Tc + trow) * Cc + h * Dc + fd * 16 + c] =
              (bf16)(oacc[fm][fd][r] * inv);
      }
    }
}

// ---------------- launch ----------------
extern "C" void kernel_launch(void* const* d_in, const int* in_sizes, int n_in,
                              void* d_out, int out_size, void* d_ws, size_t ws_size,
                              hipStream_t stream) {
  const float* x    = (const float*)d_in[0];
  const float* Wqkv = (const float*)d_in[1];
  const float* bqkv = (const float*)d_in[2];
  const float* Wout = (const float*)d_in[3];
  const float* bout = (const float*)d_in[4];
  const float* cosT = (const float*)d_in[5];
  const float* sinT = (const float*)d_in[6];
  const int*   npfx = (const int*)d_in[7];

  char* ws = (char*)d_ws;
  size_t off = 0;
  auto alloc = [&](size_t bytes) {
    char* p = ws + off;
    off = (off + bytes + 255) & ~(size_t)255;
    return p;
  };
  bf16* xb  = (bf16*)alloc((size_t)MPAD * 1024 * 2);   // also reused as y2d
  bf16* Wt1 = (bf16*)alloc((size_t)3072 * 1024 * 2);
  bf16* Wt2 = (bf16*)alloc((size_t)1024 * 1024 * 2);
  bf16* qkv = (bf16*)alloc((size_t)MPAD * 3072 * 2);
  bf16* Qh  = (bf16*)alloc((size_t)256 * TPAD * 64 * 2);
  bf16* Kh  = (bf16*)alloc((size_t)256 * TPAD * 64 * 2);
  bf16* Vt  = (bf16*)alloc((size_t)256 * TPAD * 64 * 2);
  bf16* y2d = xb;
  if (off > ws_size) return;  // workspace too small; fail loudly via wrong output

  cast_x<<<dim3(MPAD * 1024 / 2048), dim3(256), 0, stream>>>(x, xb);
  transpose_cast<<<dim3(3072 / 32, 1024 / 32), dim3(256), 0, stream>>>(Wqkv, Wt1, 1024, 3072);
  transpose_cast<<<dim3(1024 / 32, 1024 / 32), dim3(256), 0, stream>>>(Wout, Wt2, 1024, 1024);
  gemm_bt<true><<<dim3(3072 / 128, MPAD / 128), dim3(256), 0, stream>>>(
      xb, Wt1, bqkv, (void*)qkv, 3072, 1024, MPAD);
  rope_qk<<<dim3(Bc * TPAD), dim3(256), 0, stream>>>(qkv, cosT, sinT, npfx, Qh, Kh);
  vtrans<<<dim3(256 * NQT), dim3(256), 0, stream>>>(qkv, Vt);
  attn<<<dim3(256 * NQT), dim3(64), 0, stream>>>(Qh, Kh, Vt, y2d);
  gemm_bt<false><<<dim3(1024 / 128, MPAD / 128), dim3(256), 0, stream>>>(
      y2d, Wt2, bout, d_out, 1024, 1024, Bc * Tc);
}

// Round 2
// 527.205 us; speedup vs baseline: 1.1670x; 1.1670x over previous
//
#include <hip/hip_runtime.h>
#include <hip/hip_bf16.h>
#include <stdint.h>

typedef __bf16 bf16;
typedef bf16 bf16x8 __attribute__((ext_vector_type(8)));
typedef bf16 bf16x4 __attribute__((ext_vector_type(4)));
typedef float f32x4 __attribute__((ext_vector_type(4)));

#define DEV static __device__ __forceinline__

constexpr int Bc = 16, Tc = 1029, Cc = 1024, Hc = 16, Dc = 64;
constexpr int KPAD = 1088;     // 17 * 64  (K/V padded length)
constexpr int QPAD = 1152;     // 9 * 128  (Q padded length)
constexpr int MPAD = 16512;    // 129 * 128
constexpr int NKT  = KPAD / 64;   // 17
constexpr int NVT  = KPAD / 32;   // 34

DEV void gload16(void* lds_dst, const void* gsrc) {
  __builtin_amdgcn_global_load_lds(
      (const __attribute__((address_space(1))) void*)gsrc,
      (__attribute__((address_space(3))) void*)lds_dst, 16, 0, 0);
}

// ---------------- cast x (f32 -> bf16), zero pad rows ----------------
__global__ __launch_bounds__(256) void cast_x(const float* __restrict__ x,
                                              bf16* __restrict__ xb) {
  const size_t i = ((size_t)blockIdx.x * 256 + threadIdx.x) * 8;
  const int row = (int)(i >> 10);
  bf16x8 o = {};
  if (row < Bc * Tc) {
    const float4* p = (const float4*)(x + i);
    float4 a = p[0], b = p[1];
    o[0] = (bf16)a.x; o[1] = (bf16)a.y; o[2] = (bf16)a.z; o[3] = (bf16)a.w;
    o[4] = (bf16)b.x; o[5] = (bf16)b.y; o[6] = (bf16)b.z; o[7] = (bf16)b.w;
  }
  *(bf16x8*)(xb + i) = o;
}

// ---------------- transpose + cast: W[rows][cols] f32 -> Wt[cols][rows] bf16
__global__ __launch_bounds__(256) void transpose_cast(const float* __restrict__ W,
                                                      bf16* __restrict__ Wt,
                                                      int rows, int cols) {
  __shared__ float tile[32][33];
  const int c0 = blockIdx.x * 32;
  const int r0 = blockIdx.y * 32;
  const int tr = threadIdx.x >> 5;   // 0..7
  const int tc = threadIdx.x & 31;   // 0..31
#pragma unroll
  for (int j = 0; j < 4; ++j)
    tile[tr + j * 8][tc] = W[(size_t)(r0 + tr + j * 8) * cols + c0 + tc];
  __syncthreads();
#pragma unroll
  for (int j = 0; j < 4; ++j)
    Wt[(size_t)(c0 + tr + j * 8) * rows + r0 + tc] = (bf16)tile[tc][tr + j * 8];
}

// ---------------- GEMM: C = A @ Bt^T + bias ----------------
template <bool OUT_BF16>
__global__ __launch_bounds__(256) void gemm_bt(const bf16* __restrict__ A,
                                               const bf16* __restrict__ Bt,
                                               const float* __restrict__ bias,
                                               void* __restrict__ Cout,
                                               int N, int K, int Mlim) {
  constexpr int BM = 128, BN = 128, BK = 32;
  __shared__ bf16 As[2][BM * BK];
  __shared__ bf16 Bs[2][BN * BK];
  const int tid  = threadIdx.x;
  const int lane = tid & 63;
  const int wave = tid >> 6;
  const int g = lane >> 4;
  const int c = lane & 15;
  const int m0 = blockIdx.y * BM;
  const int n0 = blockIdx.x * BN;
  const int wm = (wave >> 1) * 64;
  const int wn = (wave & 1) * 64;

  auto stage = [&](int buf, int k0) {
#pragma unroll
    for (int j = 0; j < 2; ++j) {
      int idx = j * 256 + tid;
      int row = idx >> 2, ch = idx & 3;
      gload16(&As[buf][idx * 8], A + (size_t)(m0 + row) * K + k0 + ch * 8);
    }
#pragma unroll
    for (int j = 0; j < 2; ++j) {
      int idx = j * 256 + tid;
      int row = idx >> 2, ch = idx & 3;
      gload16(&Bs[buf][idx * 8], Bt + (size_t)(n0 + row) * K + k0 + ch * 8);
    }
  };

  f32x4 acc[4][4] = {};
  stage(0, 0);
  __syncthreads();
  const int nk = K / BK;
  for (int kt = 0; kt < nk; ++kt) {
    const int buf = kt & 1;
    if (kt + 1 < nk) stage(buf ^ 1, (kt + 1) * BK);
    bf16x8 af[4], bfr[4];
#pragma unroll
    for (int i = 0; i < 4; ++i) {
      af[i]  = *(const bf16x8*)&As[buf][(wm + i * 16 + c) * BK + g * 8];
      bfr[i] = *(const bf16x8*)&Bs[buf][(wn + i * 16 + c) * BK + g * 8];
    }
#pragma unroll
    for (int i = 0; i < 4; ++i)
#pragma unroll
      for (int j = 0; j < 4; ++j)
        acc[i][j] = __builtin_amdgcn_mfma_f32_16x16x32_bf16(af[i], bfr[j], acc[i][j], 0, 0, 0);
    __syncthreads();
  }

#pragma unroll
  for (int i = 0; i < 4; ++i) {
    const int mb = m0 + wm + i * 16 + g * 4;
#pragma unroll
    for (int j = 0; j < 4; ++j) {
      const int n = n0 + wn + j * 16 + c;
      const float bv = bias[n];
#pragma unroll
      for (int r = 0; r < 4; ++r) {
        const int m = mb + r;
        if (m < Mlim) {
          float v = acc[i][j][r] + bv;
          if constexpr (OUT_BF16)
            ((bf16*)Cout)[(size_t)m * N + n] = (bf16)v;
          else
            ((float*)Cout)[(size_t)m * N + n] = v;
        }
      }
    }
  }
}

// ---------------- RoPE + reshape Q -> [bh][QPAD][64], K -> [bh][KPAD][64] ----
__global__ __launch_bounds__(256) void rope_qk(const bf16* __restrict__ qkv,
                                               const float* __restrict__ cosT,
                                               const float* __restrict__ sinT,
                                               const int* __restrict__ npfx_p,
                                               bf16* __restrict__ Qh,
                                               bf16* __restrict__ Kh) {
  const int bt = blockIdx.x;
  const int b = bt / QPAD, t = bt % QPAD;
  const int h  = threadIdx.x >> 4;
  const int d0 = (threadIdx.x & 15) * 4;
  const size_t qoff = (((size_t)(b * Hc + h)) * QPAD + t) * Dc + d0;
  const size_t koff = (((size_t)(b * Hc + h)) * KPAD + t) * Dc + d0;
  if (t >= Tc) {
    bf16x4 z = {};
    *(bf16x4*)(Qh + qoff) = z;
    if (t < KPAD) *(bf16x4*)(Kh + koff) = z;
    return;
  }
  const int npfx = *npfx_p;
  const size_t inb = ((size_t)b * Tc + t) * 3072 + h * Dc;
  bf16x4 qv = *(const bf16x4*)(qkv + inb + d0);
  bf16x4 kv = *(const bf16x4*)(qkv + inb + 1024 + d0);
  float q[4], k[4];
#pragma unroll
  for (int u = 0; u < 4; ++u) { q[u] = (float)qv[u]; k[u] = (float)kv[u]; }
  if (t >= npfx) {
    const int p  = t - npfx;
    const int dp = (d0 < 32) ? d0 + 32 : d0 - 32;
    const float sgn = (d0 < 32) ? -1.f : 1.f;
    bf16x4 qp = *(const bf16x4*)(qkv + inb + dp);
    bf16x4 kp = *(const bf16x4*)(qkv + inb + 1024 + dp);
    float4 csv = *(const float4*)(cosT + (size_t)p * Dc + d0);
    float4 snv = *(const float4*)(sinT + (size_t)p * Dc + d0);
    float cs[4] = {csv.x, csv.y, csv.z, csv.w};
    float sn[4] = {snv.x, snv.y, snv.z, snv.w};
#pragma unroll
    for (int u = 0; u < 4; ++u) {
      q[u] = q[u] * cs[u] + sgn * (float)qp[u] * sn[u];
      k[u] = k[u] * cs[u] + sgn * (float)kp[u] * sn[u];
    }
  }
  bf16x4 qo, ko;
#pragma unroll
  for (int u = 0; u < 4; ++u) {
    qo[u] = (bf16)(q[u] * 0.125f);  // fold 1/sqrt(D)
    ko[u] = (bf16)k[u];
  }
  *(bf16x4*)(Qh + qoff) = qo;
  *(bf16x4*)(Kh + koff) = ko;
}

// ---------------- V transpose -> Vt [bh][64][KPAD] ----------------
__global__ __launch_bounds__(256) void vtrans(const bf16* __restrict__ qkv,
                                              bf16* __restrict__ Vt) {
  __shared__ bf16 lds[64][40];
  const int blk = blockIdx.x;
  const int tt = blk % NVT;
  const int bh = blk / NVT;
  const int b = bh >> 4, h = bh & 15;
  const int t0 = tt * 32;
  const int tl = threadIdx.x >> 3;  // 0..31
  const int ch = threadIdx.x & 7;   // 0..7
  bf16x8 v = {};
  const int t = t0 + tl;
  if (t < Tc)
    v = *(const bf16x8*)(qkv + ((size_t)b * Tc + t) * 3072 + 2048 + h * Dc + ch * 8);
#pragma unroll
  for (int u = 0; u < 8; ++u) lds[ch * 8 + u][tl] = v[u];
  __syncthreads();
  const int d  = threadIdx.x >> 2;  // 0..63
  const int tc = threadIdx.x & 3;   // 0..3
  bf16x8 o = *(const bf16x8*)&lds[d][tc * 8];
  *(bf16x8*)(Vt + ((size_t)bh * Dc + d) * KPAD + t0 + tc * 8) = o;
}

// ---------------- flash attention: 4 waves/block, QBLK=128, KVBLK=64 -------
__global__ __launch_bounds__(256) void attn2(const bf16* __restrict__ Qh,
                                             const bf16* __restrict__ Kh,
                                             const bf16* __restrict__ Vt,
                                             bf16* __restrict__ y2d) {
  __shared__ bf16 Ks[2][64 * 64];   // [kv row][d], XOR-swizzled rows (128B)
  __shared__ bf16 Vs[2][64 * 64];   // [d row][kv], XOR-swizzled rows
  __shared__ bf16 Ps[4][32 * 64];   // per-wave P tile, swizzled
  const int bh = blockIdx.y;
  const int b = bh >> 4, h = bh & 15;
  const int tid = threadIdx.x;
  const int w = tid >> 6, lane = tid & 63;
  const int g = lane >> 4, c = lane & 15;
  const int q0 = blockIdx.x * 128 + w * 32;
  const bf16* Qb = Qh + (size_t)bh * QPAD * Dc;
  const bf16* Kb = Kh + (size_t)bh * KPAD * Dc;
  const bf16* Vb = Vt + (size_t)bh * Dc * KPAD;
  char* Pw = (char*)&Ps[w][0];

  auto stage = [&](int buf, int k0) {
#pragma unroll
    for (int j = 0; j < 2; ++j) {
      int idx = j * 256 + tid;            // 512 x 16B chunks = 8KB
      int row = idx >> 3;
      int scb = ((idx & 7) << 4) ^ ((row & 7) << 4);  // pre-swizzled source col
      gload16((char*)&Ks[buf][0] + idx * 16,
              (const char*)(Kb + (size_t)(k0 + row) * 64) + scb);
    }
#pragma unroll
    for (int j = 0; j < 2; ++j) {
      int idx = j * 256 + tid;
      int row = idx >> 3;
      int scb = ((idx & 7) << 4) ^ ((row & 7) << 4);
      gload16((char*)&Vs[buf][0] + idx * 16,
              (const char*)(Vb + (size_t)row * KPAD + k0) + scb);
    }
  };

  // Q fragments (global, bf16x8)
  bf16x8 qf[2][2];
#pragma unroll
  for (int fm = 0; fm < 2; ++fm)
#pragma unroll
    for (int kc = 0; kc < 2; ++kc)
      qf[fm][kc] = *(const bf16x8*)(Qb + (size_t)(q0 + fm * 16 + c) * Dc + kc * 32 + g * 8);

  float mrun[2][4], lrun[2][4];
  f32x4 oacc[2][4] = {};
#pragma unroll
  for (int fm = 0; fm < 2; ++fm)
#pragma unroll
    for (int r = 0; r < 4; ++r) { mrun[fm][r] = -1e30f; lrun[fm][r] = 0.f; }

  stage(0, 0);
  __syncthreads();

  for (int kt = 0; kt < NKT; ++kt) {
    const int buf = kt & 1;
    const int k0 = kt * 64;
    if (kt + 1 < NKT) stage(buf ^ 1, (kt + 1) * 64);

    // --- QK^T: S[32 q][64 k] ---
    bf16x8 kf[4][2];
#pragma unroll
    for (int fn = 0; fn < 4; ++fn) {
      const int row = fn * 16 + c;
      const int sw = (row & 7) << 4;
#pragma unroll
      for (int kc = 0; kc < 2; ++kc)
        kf[fn][kc] = *(const bf16x8*)((const char*)&Ks[buf][0] + row * 128 +
                                      ((kc * 64 + g * 16) ^ sw));
    }
    f32x4 s[2][4] = {};
#pragma unroll
    for (int fn = 0; fn < 4; ++fn)
#pragma unroll
      for (int kc = 0; kc < 2; ++kc)
#pragma unroll
        for (int fm = 0; fm < 2; ++fm)
          s[fm][fn] = __builtin_amdgcn_mfma_f32_16x16x32_bf16(qf[fm][kc], kf[fn][kc], s[fm][fn], 0, 0, 0);

    if (k0 + 64 > Tc) {
#pragma unroll
      for (int fn = 0; fn < 4; ++fn)
        if (k0 + fn * 16 + c >= Tc) {
#pragma unroll
          for (int fm = 0; fm < 2; ++fm)
#pragma unroll
            for (int r = 0; r < 4; ++r) s[fm][fn][r] = -1e30f;
        }
    }

    // --- online softmax with defer-max ---
#pragma unroll
    for (int fm = 0; fm < 2; ++fm) {
      f32x4 mx;
#pragma unroll
      for (int r = 0; r < 4; ++r)
        mx[r] = fmaxf(fmaxf(s[fm][0][r], s[fm][1][r]), fmaxf(s[fm][2][r], s[fm][3][r]));
#pragma unroll
      for (int msk = 1; msk < 16; msk <<= 1)
#pragma unroll
        for (int r = 0; r < 4; ++r) mx[r] = fmaxf(mx[r], __shfl_xor(mx[r], msk));
      const bool allok = (mx[0] - mrun[fm][0] <= 8.f) && (mx[1] - mrun[fm][1] <= 8.f) &&
                         (mx[2] - mrun[fm][2] <= 8.f) && (mx[3] - mrun[fm][3] <= 8.f);
      if (!__all(allok)) {
#pragma unroll
        for (int r = 0; r < 4; ++r) {
          const float mnew = fmaxf(mrun[fm][r], mx[r]);
          const float al = __expf(mrun[fm][r] - mnew);
          mrun[fm][r] = mnew;
          lrun[fm][r] *= al;
#pragma unroll
          for (int fd = 0; fd < 4; ++fd) oacc[fm][fd][r] *= al;
        }
      }
      f32x4 psum = {};
#pragma unroll
      for (int fn = 0; fn < 4; ++fn)
#pragma unroll
        for (int r = 0; r < 4; ++r) {
          const float p = __expf(s[fm][fn][r] - mrun[fm][r]);
          psum[r] += p;
          const int row = fm * 16 + g * 4 + r;
          *(bf16*)(Pw + row * 128 + (((fn * 16 + c) * 2) ^ ((row & 7) << 4))) = (bf16)p;
        }
#pragma unroll
      for (int msk = 1; msk < 16; msk <<= 1)
#pragma unroll
        for (int r = 0; r < 4; ++r) psum[r] += __shfl_xor(psum[r], msk);
#pragma unroll
      for (int r = 0; r < 4; ++r) lrun[fm][r] += psum[r];
    }

    // --- PV: O += P @ V^T (Vs rows are d, k-contiguous) ---
    bf16x8 pf[2][2];
#pragma unroll
    for (int fm = 0; fm < 2; ++fm) {
      const int row = fm * 16 + c;
      const int sw = (row & 7) << 4;
#pragma unroll
      for (int kc = 0; kc < 2; ++kc)
        pf[fm][kc] = *(const bf16x8*)(Pw + row * 128 + ((kc * 64 + g * 16) ^ sw));
    }
#pragma unroll
    for (int fd = 0; fd < 4; ++fd) {
      const int row = fd * 16 + c;
      const int sw = (row & 7) << 4;
#pragma unroll
      for (int kc = 0; kc < 2; ++kc) {
        bf16x8 vf = *(const bf16x8*)((const char*)&Vs[buf][0] + row * 128 +
                                     ((kc * 64 + g * 16) ^ sw));
#pragma unroll
        for (int fm = 0; fm < 2; ++fm)
          oacc[fm][fd] = __builtin_amdgcn_mfma_f32_16x16x32_bf16(pf[fm][kc], vf, oacc[fm][fd], 0, 0, 0);
      }
    }
    __syncthreads();
  }

#pragma unroll
  for (int fm = 0; fm < 2; ++fm)
#pragma unroll
    for (int r = 0; r < 4; ++r) {
      const int trow = q0 + fm * 16 + g * 4 + r;
      if (trow < Tc) {
        const float inv = 1.f / lrun[fm][r];
#pragma unroll
        for (int fd = 0; fd < 4; ++fd)
          y2d[((size_t)b * Tc + trow) * Cc + h * Dc + fd * 16 + c] =
              (bf16)(oacc[fm][fd][r] * inv);
      }
    }
}

// ---------------- launch ----------------
extern "C" void kernel_launch(void* const* d_in, const int* in_sizes, int n_in,
                              void* d_out, int out_size, void* d_ws, size_t ws_size,
                              hipStream_t stream) {
  const float* x    = (const float*)d_in[0];
  const float* Wqkv = (const float*)d_in[1];
  const float* bqkv = (const float*)d_in[2];
  const float* Wout = (const float*)d_in[3];
  const float* bout = (const float*)d_in[4];
  const float* cosT = (const float*)d_in[5];
  const float* sinT = (const float*)d_in[6];
  const int*   npfx = (const int*)d_in[7];

  char* ws = (char*)d_ws;
  size_t off = 0;
  auto alloc = [&](size_t bytes) {
    char* p = ws + off;
    off = (off + bytes + 255) & ~(size_t)255;
    return p;
  };
  bf16* xb  = (bf16*)alloc((size_t)MPAD * 1024 * 2);   // also reused as y2d
  bf16* Wt1 = (bf16*)alloc((size_t)3072 * 1024 * 2);
  bf16* Wt2 = (bf16*)alloc((size_t)1024 * 1024 * 2);
  bf16* qkv = (bf16*)alloc((size_t)MPAD * 3072 * 2);
  bf16* Qh  = (bf16*)alloc((size_t)256 * QPAD * 64 * 2);
  bf16* Kh  = (bf16*)alloc((size_t)256 * KPAD * 64 * 2);
  bf16* Vt  = (bf16*)alloc((size_t)256 * KPAD * 64 * 2);
  bf16* y2d = xb;
  if (off > ws_size) return;

  cast_x<<<dim3(MPAD * 1024 / 2048), dim3(256), 0, stream>>>(x, xb);
  transpose_cast<<<dim3(3072 / 32, 1024 / 32), dim3(256), 0, stream>>>(Wqkv, Wt1, 1024, 3072);
  transpose_cast<<<dim3(1024 / 32, 1024 / 32), dim3(256), 0, stream>>>(Wout, Wt2, 1024, 1024);
  gemm_bt<true><<<dim3(3072 / 128, MPAD / 128), dim3(256), 0, stream>>>(
      xb, Wt1, bqkv, (void*)qkv, 3072, 1024, MPAD);
  rope_qk<<<dim3(Bc * QPAD), dim3(256), 0, stream>>>(qkv, cosT, sinT, npfx, Qh, Kh);
  vtrans<<<dim3(256 * NVT), dim3(256), 0, stream>>>(qkv, Vt);
  attn2<<<dim3(QPAD / 128, 256), dim3(256), 0, stream>>>(Qh, Kh, Vt, y2d);
  gemm_bt<false><<<dim3(1024 / 128, MPAD / 128), dim3(256), 0, stream>>>(
      y2d, Wt2, bout, d_out, 1024, 1024, Bc * Tc);
}